// Round 2
// 605.063 us; speedup vs baseline: 1.1331x; 1.1331x over previous
//
#include <hip/hip_runtime.h>

#define TOTAL_B 65536
#define NKR 1024   // K*RANK = 64*16
#define ZD 128

// ---------------------------------------------------------------------------
// Kernel 1: w = z @ W^T + b + 1e-6   (fp32)
//  - fragment cols/rows split as {t*4..t*4+3} u {64+t*4..+3}: ds_read_b128
//    lane stride is 16B -> 2-way bank aliasing (free, m136) instead of the
//    32B-stride 4-way conflict of the old {t*8..t*8+7} mapping.
//  - register double-buffered staging: next K-tile's global loads issue
//    before the 32-k FMA block so HBM latency hides under compute.
// Output is bit-identical to the verified round-0 version (same FMA order).
// ---------------------------------------------------------------------------
__global__ __launch_bounds__(256) void gemm_zwt(
    const float* __restrict__ z, const float* __restrict__ W,
    const float* __restrict__ bias, float* __restrict__ out)
{
    __shared__ float zs[32][132];
    __shared__ float ws[32][132];

    const int tid = threadIdx.x;
    const int tx = tid & 15;
    const int ty = tid >> 4;
    const int m0 = blockIdx.y * 128;
    const int n0 = blockIdx.x * 128;

    float acc[8][8];
    #pragma unroll
    for (int i = 0; i < 8; ++i)
        #pragma unroll
        for (int j = 0; j < 8; ++j) acc[i][j] = 0.f;

    const int kq = (tid & 7) * 4;   // k-offset within tile (float4 aligned)
    const int mr = tid >> 3;        // row 0..31 within 32-row staging slice

    const float* gz = z + (size_t)(m0 + mr) * ZD + kq;
    const float* gw = W + (size_t)(n0 + mr) * ZD + kq;

    // prefetch tile 0
    float4 vz[4], vw[4];
    #pragma unroll
    for (int p = 0; p < 4; ++p) {
        vz[p] = *(const float4*)(gz + (size_t)p * 32 * ZD);
        vw[p] = *(const float4*)(gw + (size_t)p * 32 * ZD);
    }

    #pragma unroll
    for (int kc = 0; kc < ZD; kc += 32) {
        // write staged tile (transpose to [k][row])
        #pragma unroll
        for (int p = 0; p < 4; ++p) {
            int ml = mr + p * 32;
            zs[kq + 0][ml] = vz[p].x; zs[kq + 1][ml] = vz[p].y;
            zs[kq + 2][ml] = vz[p].z; zs[kq + 3][ml] = vz[p].w;
            ws[kq + 0][ml] = vw[p].x; ws[kq + 1][ml] = vw[p].y;
            ws[kq + 2][ml] = vw[p].z; ws[kq + 3][ml] = vw[p].w;
        }
        __syncthreads();

        // prefetch next tile into registers (hidden under compute below)
        if (kc + 32 < ZD) {
            #pragma unroll
            for (int p = 0; p < 4; ++p) {
                vz[p] = *(const float4*)(gz + (size_t)p * 32 * ZD + kc + 32);
                vw[p] = *(const float4*)(gw + (size_t)p * 32 * ZD + kc + 32);
            }
        }

        #pragma unroll 8
        for (int k = 0; k < 32; ++k) {
            float4 a0 = *(const float4*)&zs[k][ty * 4];
            float4 a1 = *(const float4*)&zs[k][64 + ty * 4];
            float4 c0 = *(const float4*)&ws[k][tx * 4];
            float4 c1 = *(const float4*)&ws[k][64 + tx * 4];
            float zr[8] = {a0.x, a0.y, a0.z, a0.w, a1.x, a1.y, a1.z, a1.w};
            float wr[8] = {c0.x, c0.y, c0.z, c0.w, c1.x, c1.y, c1.z, c1.w};
            #pragma unroll
            for (int i = 0; i < 8; ++i)
                #pragma unroll
                for (int j = 0; j < 8; ++j)
                    acc[i][j] = fmaf(zr[i], wr[j], acc[i][j]);
        }
        __syncthreads();
    }

    float bv0[4], bv1[4];
    #pragma unroll
    for (int j = 0; j < 4; ++j) {
        bv0[j] = bias[n0 + tx * 4 + j] + 1e-6f;
        bv1[j] = bias[n0 + 64 + tx * 4 + j] + 1e-6f;
    }

    #pragma unroll
    for (int i = 0; i < 8; ++i) {
        int row = (i < 4) ? (ty * 4 + i) : (64 + ty * 4 + i - 4);
        size_t base = (size_t)(m0 + row) * NKR + n0;
        float4 o0, o1;
        o0.x = acc[i][0] + bv0[0]; o0.y = acc[i][1] + bv0[1];
        o0.z = acc[i][2] + bv0[2]; o0.w = acc[i][3] + bv0[3];
        o1.x = acc[i][4] + bv1[0]; o1.y = acc[i][5] + bv1[1];
        o1.z = acc[i][6] + bv1[2]; o1.w = acc[i][7] + bv1[3];
        *(float4*)(out + base + tx * 4) = o0;
        *(float4*)(out + base + 64 + tx * 4) = o1;
    }
}

// ---------------------------------------------------------------------------
// Kernel 2: batched Householder QR, 16 lanes per matrix (4 matrices/wave),
// lane q holds rows {q, q+16, q+32, q+48}.
//  - rsum16 via __builtin_amdgcn_update_dpp (compiler inserts the mandatory
//    VALU->DPP hazard s_nops; inline-asm DPP without them corrupts data).
//  - slarfg scalars via __builtin_amdgcn_sqrtf / rcpf (1-ulp, off critical
//    libm expansion path).
//  - Q formed by a single descending sorg2r sweep that overwrites a[j] in
//    place with Q column j: 120 reflector applications instead of 160
//    guarded ones, all 16 Q columns finish in registers, epilogue writes
//    full 64B rows (no partial-cacheline RMW write amplification).
// ---------------------------------------------------------------------------
template <int CTRL>
__device__ __forceinline__ float dpp_add(float v) {
    int x = __builtin_amdgcn_update_dpp(0, __float_as_int(v), CTRL, 0xF, 0xF, false);
    return v + __int_as_float(x);
}

// allreduce-sum over each aligned 16-lane group; identical value on all 16
// lanes (rotation butterfly -> same combine order on every lane).
__device__ __forceinline__ float rsum16(float v) {
    v = dpp_add<0x128>(v);   // row_ror:8
    v = dpp_add<0x124>(v);   // row_ror:4
    v = dpp_add<0x122>(v);   // row_ror:2
    v = dpp_add<0x121>(v);   // row_ror:1
    return v;
}

__global__ __launch_bounds__(256) void qr_batched(float* __restrict__ buf)
{
    const int tid = threadIdx.x;
    const int lq = tid & 15;                         // lane within 16-group
    const int item = (blockIdx.x * 256 + tid) >> 4;  // one matrix per group

    float* p = buf + (size_t)item * NKR + lq * 16;   // row lq, col 0

    // load: a[c][i] = A[lq + 16*i][c]
    float a[16][4];
    #pragma unroll
    for (int i = 0; i < 4; ++i) {
        #pragma unroll
        for (int cc = 0; cc < 16; cc += 4) {
            float4 v = *(const float4*)(p + i * 256 + cc);
            a[cc + 0][i] = v.x; a[cc + 1][i] = v.y;
            a[cc + 2][i] = v.z; a[cc + 3][i] = v.w;
        }
    }

    float tau[16];

    // ---- factorization (LAPACK sgeqr2 / slarfg convention) ----
    #pragma unroll
    for (int j = 0; j < 16; ++j) {
        float x0 = a[j][0], x1 = a[j][1], x2 = a[j][2], x3 = a[j][3];
        // rows lq+16, lq+32, lq+48 are always > j (j < 16); row lq only if lq > j
        float x0m = (lq > j) ? x0 : 0.f;
        float pp = fmaf(x0m, x0m, fmaf(x1, x1, fmaf(x2, x2, x3 * x3)));
        float xn2   = rsum16(pp);
        float alpha = rsum16((lq == j) ? x0 : 0.f);

        float rr   = __builtin_amdgcn_sqrtf(fmaf(alpha, alpha, xn2));
        float beta = (alpha >= 0.f) ? -rr : rr;
        float dba  = beta - alpha;
        float tj   = dba * __builtin_amdgcn_rcpf(beta);
        float sc   = -__builtin_amdgcn_rcpf(dba);
        if (xn2 == 0.f) { tj = 0.f; sc = 0.f; }
        tau[j] = tj;

        float v0 = (lq == j) ? 1.f : ((lq > j) ? x0 * sc : 0.f);
        float v1 = x1 * sc, v2 = x2 * sc, v3 = x3 * sc;
        a[j][0] = v0; a[j][1] = v1; a[j][2] = v2; a[j][3] = v3;

        #pragma unroll
        for (int c = j + 1; c < 16; ++c) {
            float d = rsum16(fmaf(v0, a[c][0],
                        fmaf(v1, a[c][1],
                        fmaf(v2, a[c][2], v3 * a[c][3]))));
            float t = -tj * d;
            a[c][0] = fmaf(t, v0, a[c][0]);
            a[c][1] = fmaf(t, v1, a[c][1]);
            a[c][2] = fmaf(t, v2, a[c][2]);
            a[c][3] = fmaf(t, v3, a[c][3]);
        }
    }

    // ---- form Q (sorg2r, descending sweep, in place) ----
    // At step j: columns j+1..15 already hold Q_{j+1..15} under H_{j+1..15};
    // apply H_j to them, then column j itself becomes H_j e_j = e_j - tau*v.
    // Reflector a[j] dies exactly when Q column j is born -> no extra regs.
    #pragma unroll
    for (int j = 15; j >= 0; --j) {
        float tj = tau[j];
        float v0 = a[j][0], v1 = a[j][1], v2 = a[j][2], v3 = a[j][3];
        #pragma unroll
        for (int c = j + 1; c < 16; ++c) {
            float d = rsum16(fmaf(v0, a[c][0],
                        fmaf(v1, a[c][1],
                        fmaf(v2, a[c][2], v3 * a[c][3]))));
            float t = -tj * d;
            a[c][0] = fmaf(t, v0, a[c][0]);
            a[c][1] = fmaf(t, v1, a[c][1]);
            a[c][2] = fmaf(t, v2, a[c][2]);
            a[c][3] = fmaf(t, v3, a[c][3]);
        }
        float nt = -tj;
        a[j][0] = fmaf(nt, v0, (lq == j) ? 1.f : 0.f);
        a[j][1] = nt * v1;
        a[j][2] = nt * v2;
        a[j][3] = nt * v3;
    }

    // ---- store Q: full 64B rows; lanes 0..15 cover 16 consecutive rows ----
    #pragma unroll
    for (int i = 0; i < 4; ++i) {
        #pragma unroll
        for (int cc = 0; cc < 16; cc += 4) {
            float4 vv = {a[cc + 0][i], a[cc + 1][i], a[cc + 2][i], a[cc + 3][i]};
            *(float4*)(p + i * 256 + cc) = vv;
        }
    }
}

extern "C" void kernel_launch(void* const* d_in, const int* in_sizes, int n_in,
                              void* d_out, int out_size, void* d_ws, size_t ws_size,
                              hipStream_t stream) {
    const float* z = (const float*)d_in[0];
    const float* W = (const float*)d_in[1];
    const float* b = (const float*)d_in[2];
    float* out = (float*)d_out;

    dim3 ggrid(NKR / 128, TOTAL_B / 128);   // (8, 512)
    hipLaunchKernelGGL(gemm_zwt, ggrid, dim3(256), 0, stream, z, W, b, out);
    hipLaunchKernelGGL(qr_batched, dim3(TOTAL_B / 16), dim3(256), 0, stream, out);
}